// Round 10
// baseline (129.866 us; speedup 1.0000x reference)
//
#include <hip/hip_runtime.h>
#include <math.h>

#define BATCH 2
#define SEQ   2048
#define HIDDEN 1024
#define HEADS 16
#define HD    64
#define QSCALE 0.18033688011112042f   // log2(e)/8 : scores computed in exp2 domain

typedef __attribute__((ext_vector_type(8)))  short short8;
typedef __attribute__((ext_vector_type(16))) float f32x16;

__device__ __forceinline__ unsigned short f2bf(float f) {
    unsigned int u = __builtin_bit_cast(unsigned int, f);
    u = (u + 0x7FFFu + ((u >> 16) & 1u)) >> 16;   // round-to-nearest-even
    return (unsigned short)u;
}
__device__ __forceinline__ float bf2f(unsigned short h) {
    unsigned int u = ((unsigned int)h) << 16;
    return __builtin_bit_cast(float, u);
}
__device__ __forceinline__ unsigned int cvt_pk_bf16(float lo, float hi) {
    unsigned int r;
    asm("v_cvt_pk_bf16_f32 %0, %1, %2" : "=v"(r) : "v"(lo), "v"(hi));
    return r;
}
__device__ __forceinline__ void gl16(const void* g, void* l) {
    __builtin_amdgcn_global_load_lds(
        (const __attribute__((address_space(1))) void*)g,
        (__attribute__((address_space(3))) void*)l,
        16, 0, 0);
}
#define WAIT_VM(N) asm volatile("s_waitcnt vmcnt(" #N ")" ::: "memory")
#define BARRIER()  do { __builtin_amdgcn_s_barrier(); __builtin_amdgcn_sched_barrier(0); } while (0)

// ---------------------------------------------------------------------------
__global__ __launch_bounds__(256)
void conv_hi(const float* __restrict__ src, unsigned short* __restrict__ hi)
{
    int idx = blockIdx.x * 256 + threadIdx.x;
    float4 v = ((const float4*)src)[idx];
    ushort4 h4;
    h4.x = f2bf(v.x); h4.y = f2bf(v.y); h4.z = f2bf(v.z); h4.w = f2bf(v.w);
    ((ushort4*)hi)[idx] = h4;
}

// ---------------------------------------------------------------------------
// Single-bf16 GEMM core (R9-frozen).
// ---------------------------------------------------------------------------
__device__ __forceinline__ void gemm_core1(
    const char* Ah, const char* Bh,
    int m0, int n0, char* smem, f32x16 acc[2][2])
{
    const int t    = threadIdx.x;
    const int lane = t & 63;
    const int w    = t >> 6;
    const int wm   = w >> 1, wn = w & 1;
    const int l31  = lane & 31, hh = lane >> 5;

    auto stage = [&](int buf, int kt) {
        #pragma unroll
        for (int i = 0; i < 2; ++i) {
            int r  = i * 64 + (t >> 2);
            int cs = (t & 3) ^ ((r >> 1) & 3);
            gl16(Ah + ((size_t)(m0 + r) * 1024 + kt * 32 + cs * 8) * 2,
                 smem + buf * 16384 + i * 4096 + w * 1024);
            gl16(Bh + ((size_t)(n0 + r) * 1024 + kt * 32 + cs * 8) * 2,
                 smem + buf * 16384 + 8192 + i * 4096 + w * 1024);
        }
    };

    stage(0, 0);
    __syncthreads();

    for (int kt = 0; kt < 32; ++kt) {
        if (kt + 1 < 32) stage((kt & 1) ^ 1, kt + 1);
        const char* Ab = smem + (kt & 1) * 16384;
        const char* Bb = Ab + 8192;
        #pragma unroll
        for (int ks = 0; ks < 2; ++ks) {
            short8 ah[2], bh[2];
            #pragma unroll
            for (int mt = 0; mt < 2; ++mt) {
                int R  = wm * 64 + mt * 32 + l31;
                int ch = ((ks * 2 + hh) ^ ((R >> 1) & 3)) * 16;
                ah[mt] = *(const short8*)(Ab + R * 64 + ch);
            }
            #pragma unroll
            for (int nt = 0; nt < 2; ++nt) {
                int R  = wn * 64 + nt * 32 + l31;
                int ch = ((ks * 2 + hh) ^ ((R >> 1) & 3)) * 16;
                bh[nt] = *(const short8*)(Bb + R * 64 + ch);
            }
            #pragma unroll
            for (int mt = 0; mt < 2; ++mt)
                #pragma unroll
                for (int nt = 0; nt < 2; ++nt)
                    acc[mt][nt] = __builtin_amdgcn_mfma_f32_32x32x16_bf16(ah[mt], bh[nt], acc[mt][nt], 0, 0, 0);
        }
        __syncthreads();
    }
}

// ---------------------------------------------------------------------------
// QKV GEMM (R9-frozen).
// ---------------------------------------------------------------------------
__global__ __launch_bounds__(256, 3)
void qkv_gemm(const unsigned short* __restrict__ xh,
              const unsigned short* __restrict__ wh,
              const float* __restrict__ bias,
              unsigned short* __restrict__ qB, unsigned short* __restrict__ kB,
              unsigned short* __restrict__ vtB)
{
    __shared__ __align__(16) char smem[34816];
    f32x16 acc[2][2] = {{{}, {}}, {{}, {}}};
    const int m0 = blockIdx.x * 128, n0 = blockIdx.y * 128;
    gemm_core1((const char*)xh, (const char*)wh, m0, n0, smem, acc);

    const int t    = threadIdx.x;
    const int lane = t & 63;
    const int w    = t >> 6;
    const int wm   = w >> 1, wn = w & 1;
    const int l31  = lane & 31, hh = lane >> 5;

    const int which = n0 >> 10;            // 0=q 1=k 2=v
    const float scl = (which == 0) ? QSCALE : 1.0f;

    #pragma unroll
    for (int mt = 0; mt < 2; ++mt)
        #pragma unroll
        for (int nt = 0; nt < 2; ++nt) {
            int nl = wn * 64 + nt * 32 + l31;
            float bb = bias[n0 + nl];
            #pragma unroll
            for (int r = 0; r < 16; ++r) {
                int ml = wm * 64 + mt * 32 + (r & 3) + 8 * (r >> 2) + 4 * hh;
                float val = (acc[mt][nt][r] + bb) * scl;
                *(unsigned short*)(smem + ml * 272 + nl * 2) = f2bf(val);
            }
        }
    __syncthreads();

    const int hbase = (n0 & 1023) >> 6;
    const int b     = m0 >> 11;
    const int s0    = m0 & 2047;

    if (which < 2) {
        unsigned short* pp = which ? kB : qB;
        const int nc   = t & 31;
        const int head = hbase + (nc >> 4);
        const int d0   = (nc & 15) * 4;
        #pragma unroll
        for (int it = 0; it < 16; ++it) {
            int m = it * 8 + (t >> 5);
            ushort4 h4 = *(const ushort4*)(smem + m * 272 + nc * 8);
            size_t idx = (((size_t)(b * HEADS + head)) * SEQ + s0 + m) * HD + d0;
            *(ushort4*)&pp[idx] = h4;
        }
    } else {
        const int nl   = t & 127;
        const int head = hbase + (nl >> 6);
        const int d    = nl & 63;
        #pragma unroll
        for (int it = 0; it < 16; ++it) {
            int mq = it * 2 + (t >> 7);
            ushort4 h4;
            h4.x = *(const unsigned short*)(smem + (mq * 4 + 0) * 272 + nl * 2);
            h4.y = *(const unsigned short*)(smem + (mq * 4 + 1) * 272 + nl * 2);
            h4.z = *(const unsigned short*)(smem + (mq * 4 + 2) * 272 + nl * 2);
            h4.w = *(const unsigned short*)(smem + (mq * 4 + 3) * 272 + nl * 2);
            size_t idx = (((size_t)(b * HEADS + head)) * HD + d) * SEQ + s0 + mq * 4;
            *(ushort4*)&vtB[idx] = h4;
        }
    }
}

// ---------------------------------------------------------------------------
// Output projection GEMM (R9-frozen).
// ---------------------------------------------------------------------------
__global__ __launch_bounds__(256, 3)
void out_gemm(const unsigned short* __restrict__ cth,
              const unsigned short* __restrict__ bh_,
              const float* __restrict__ bias, float* __restrict__ out)
{
    __shared__ __align__(16) char smem[32768];
    f32x16 acc[2][2] = {{{}, {}}, {{}, {}}};
    const int m0 = blockIdx.x * 128, n0 = blockIdx.y * 128;
    gemm_core1((const char*)cth, (const char*)bh_, m0, n0, smem, acc);

    const int t    = threadIdx.x;
    const int lane = t & 63;
    const int w    = t >> 6;
    const int wm   = w >> 1, wn = w & 1;
    const int l31  = lane & 31, hh = lane >> 5;

    #pragma unroll
    for (int mt = 0; mt < 2; ++mt)
        #pragma unroll
        for (int nt = 0; nt < 2; ++nt) {
            int n = n0 + wn * 64 + nt * 32 + l31;
            float bb = bias[n];
            #pragma unroll
            for (int r = 0; r < 16; ++r) {
                int m = m0 + wm * 64 + mt * 32 + (r & 3) + 8 * (r >> 2) + 4 * hh;
                out[(size_t)m * 1024 + n] = acc[mt][nt][r] + bb;
            }
        }
}

// ---------------------------------------------------------------------------
// Flash attention R10: split-K (2 halves, grid 1024), 3-buffer ring (48KB ->
// 3 blocks/CU), write-ahead 1, WAIT_VM(4). Max-free softmax makes partials
// exact plain sums: each block writes raw acc (f32, per-thread contiguous
// 128B) + lsum; combine kernel merges. Q staged transiently over ring bufs
// 1-2 (hoist fenced by lgkmcnt(0)+sched_barrier+BARRIER before stage(1)).
// ---------------------------------------------------------------------------
#define NPH 16   // K-pairs per half (SEQ/64/2)

__global__ __launch_bounds__(256, 3)
void attn_mfma(const unsigned short* __restrict__ qB, const unsigned short* __restrict__ kB,
               const unsigned short* __restrict__ vtB,
               float* __restrict__ pacc0, float* __restrict__ pacc1,
               float* __restrict__ plsum)
{
    __shared__ __align__(16) char smem[49152];
    const int t    = threadIdx.x;
    const int lane = t & 63;
    const int wq   = t >> 6;
    const int l31  = lane & 31;
    const int hh   = lane >> 5;

    // grid 1024: xcd | qt | bh-group | half  (same-XCD = 4 bh-groups)
    const int bid  = blockIdx.x;
    const int xcd  = bid & 7;
    const int r    = bid >> 3;                 // 0..127
    const int qt   = r & 15;
    const int bhg  = xcd + 8 * ((r >> 4) & 3); // 0..31
    const int half = r >> 6;                   // 0..1
    const int q0   = qt * 128;
    const size_t bh = (size_t)bhg;

    const char* qP = (const char*)(qB + bh * SEQ * HD);
    const char* kP = (const char*)(kB + bh * SEQ * HD);
    const char* vP = (const char*)(vtB + bh * SEQ * HD);

    const int wbase = wq * 1024;

    {   // Q: 128 rows x 128B into [16K,48K) (transient; ring bufs 1,2)
        int rr = t >> 3, cc = t & 7;
        #pragma unroll
        for (int i = 0; i < 4; ++i) {
            int row = i * 32 + rr;
            int ch  = cc ^ (row & 7);
            gl16(qP + (size_t)(q0 + row) * 128 + ch * 16,
                 smem + 16384 + i * 4096 + wbase);
        }
    }
    // global pair g -> ring buffer b*16384: Ka@0 Kb@4K Va@8K Vb@12K
    auto stagePair = [&](int b, int g) {
        int base = b * 16384;
        int rr = t >> 3;
        int ch = (t & 7) ^ (rr & 7);
        gl16(kP + (size_t)(g * 64 + rr) * 128 + ch * 16,      smem + base +     0 + wbase);
        gl16(kP + (size_t)(g * 64 + 32 + rr) * 128 + ch * 16, smem + base +  4096 + wbase);
        int rr2 = t >> 2;
        int s4  = (rr2 & 3) ^ ((rr2 >> 2) & 3);
        int ch2 = (t & 3) ^ s4;
        gl16(vP + (size_t)rr2 * (SEQ * 2) + g * 128 +      ch2 * 16, smem + base +  8192 + wbase);
        gl16(vP + (size_t)rr2 * (SEQ * 2) + g * 128 + 64 + ch2 * 16, smem + base + 12288 + wbase);
    };
    const int g0 = half * NPH;
    stagePair(0, g0);
    WAIT_VM(4);            // Q's 4 loads (oldest) landed
    BARRIER();

    short8 qf[4];
    {
        int qrow = 32 * wq + l31;
        #pragma unroll
        for (int ks = 0; ks < 4; ++ks) {
            int ch = ((2 * ks + hh) ^ (qrow & 7)) * 16;
            qf[ks] = *(const short8*)(smem + 16384 + qrow * 128 + ch);
        }
    }
    asm volatile("s_waitcnt lgkmcnt(0)" ::: "memory");   // hoist complete
    __builtin_amdgcn_sched_barrier(0);
    BARRIER();             // all waves hoisted before stage(1) hits Q region

    f32x16 acc0 = {}, acc1 = {};
    float lsum = 0.0f;

    for (int i = 0; i < NPH; ++i) {
        if (i + 1 < NPH) {
            int nx = i + 1;
            stagePair(nx - (nx / 3) * 3, g0 + nx);   // (i+1)%3
            WAIT_VM(4);
        } else {
            WAIT_VM(0);
        }
        BARRIER();

        const char* Pb = smem + (i - (i / 3) * 3) * 16384;

        // --- QK^T, both tiles (8 MFMA cluster) ---
        f32x16 sa = {}, sb = {};
        __builtin_amdgcn_s_setprio(1);
        #pragma unroll
        for (int ks = 0; ks < 4; ++ks) {
            int ch = ((2 * ks + hh) ^ (l31 & 7)) * 16;
            short8 ka = *(const short8*)(Pb +        l31 * 128 + ch);
            short8 kb = *(const short8*)(Pb + 4096 + l31 * 128 + ch);
            sa = __builtin_amdgcn_mfma_f32_32x32x16_bf16(ka, qf[ks], sa, 0, 0, 0);
            sb = __builtin_amdgcn_mfma_f32_32x32x16_bf16(kb, qf[ks], sb, 0, 0, 0);
        }
        __builtin_amdgcn_s_setprio(0);

        // --- exp2 direct + pack + own-half sums ---
        unsigned int pa_[8], pb_[8];
        float ps0 = 0.f, ps1 = 0.f, ps2 = 0.f, ps3 = 0.f;
        #pragma unroll
        for (int w = 0; w < 8; ++w) {
            float e0 = __builtin_amdgcn_exp2f(sa[2 * w]);
            float e1 = __builtin_amdgcn_exp2f(sa[2 * w + 1]);
            ps0 += e0; ps1 += e1;
            pa_[w] = cvt_pk_bf16(e0, e1);
            float f0 = __builtin_amdgcn_exp2f(sb[2 * w]);
            float f1 = __builtin_amdgcn_exp2f(sb[2 * w + 1]);
            ps2 += f0; ps3 += f1;
            pb_[w] = cvt_pk_bf16(f0, f1);
        }
        lsum += (ps0 + ps1) + (ps2 + ps3);

        // --- PV, both tiles; B-frags via permlane32 half-swap ---
        const char* Va = Pb + 8192;
        const char* Vb = Pb + 12288;
        __builtin_amdgcn_s_setprio(1);
        #pragma unroll
        for (int ks = 0; ks < 2; ++ks) {
            unsigned int a0 = pa_[4*ks],     a2 = pa_[4*ks + 2];
            unsigned int a1 = pa_[4*ks + 1], a3 = pa_[4*ks + 3];
            asm volatile("v_permlane32_swap_b32 %0, %1" : "+v"(a0), "+v"(a2));
            asm volatile("v_permlane32_swap_b32 %0, %1" : "+v"(a1), "+v"(a3));
            unsigned int b0 = pb_[4*ks],     b2 = pb_[4*ks + 2];
            unsigned int b1 = pb_[4*ks + 1], b3 = pb_[4*ks + 3];
            asm volatile("v_permlane32_swap_b32 %0, %1" : "+v"(b0), "+v"(b2));
            asm volatile("v_permlane32_swap_b32 %0, %1" : "+v"(b1), "+v"(b3));
            short8 pA = __builtin_bit_cast(short8, make_uint4(a0, a1, a2, a3));
            short8 pB = __builtin_bit_cast(short8, make_uint4(b0, b1, b2, b3));
            #pragma unroll
            for (int mt = 0; mt < 2; ++mt) {
                int rrow = 32 * mt + l31;
                int s4   = (rrow & 3) ^ ((rrow >> 2) & 3);
                int ch   = ((2 * ks + hh) ^ s4) * 16;
                short8 va = *(const short8*)(Va + rrow * 64 + ch);
                short8 vb = *(const short8*)(Vb + rrow * 64 + ch);
                if (mt == 0) {
                    acc0 = __builtin_amdgcn_mfma_f32_32x32x16_bf16(va, pA, acc0, 0, 0, 0);
                    acc0 = __builtin_amdgcn_mfma_f32_32x32x16_bf16(vb, pB, acc0, 0, 0, 0);
                } else {
                    acc1 = __builtin_amdgcn_mfma_f32_32x32x16_bf16(va, pA, acc1, 0, 0, 0);
                    acc1 = __builtin_amdgcn_mfma_f32_32x32x16_bf16(vb, pB, acc1, 0, 0, 0);
                }
            }
        }
        __builtin_amdgcn_s_setprio(0);
    }

    // --- epilogue: write raw partials (no normalize), coalesced 128B/thread
    lsum += __shfl_xor(lsum, 32, 64);
    const int tile = bhg * 16 + qt;
    float* dst = (half ? pacc1 : pacc0) + (size_t)tile * 8192 + t * 32;
    #pragma unroll
    for (int m2 = 0; m2 < 4; ++m2) {
        *(float4*)(dst + m2 * 4)      = make_float4(acc0[4*m2+0], acc0[4*m2+1], acc0[4*m2+2], acc0[4*m2+3]);
        *(float4*)(dst + 16 + m2 * 4) = make_float4(acc1[4*m2+0], acc1[4*m2+1], acc1[4*m2+2], acc1[4*m2+3]);
    }
    if (hh == 0)
        plsum[(size_t)(half * 512 + tile) * 128 + 32 * wq + l31] = lsum;
}

// ---------------------------------------------------------------------------
// Combine: ctx = (A+B)/(lA+lB), bf16, LDS-transpose, store ctx [b*s][1024].
// Grid 512 (one block per tile), 256 threads.
// ---------------------------------------------------------------------------
__global__ __launch_bounds__(256, 2)
void attn_combine(const float* __restrict__ pacc0, const float* __restrict__ pacc1,
                  const float* __restrict__ plsum, unsigned short* __restrict__ ctxb)
{
    __shared__ __align__(16) char smem[16384];
    const int t    = threadIdx.x;
    const int lane = t & 63;
    const int wq   = t >> 6;
    const int l31  = lane & 31;
    const int hh   = lane >> 5;
    const int tile = blockIdx.x;
    const int bhg  = tile >> 4;
    const int q0   = (tile & 15) * 128;
    const int q    = 32 * wq + l31;

    const float* A = pacc0 + (size_t)tile * 8192 + t * 32;
    const float* B = pacc1 + (size_t)tile * 8192 + t * 32;
    float l0 = plsum[(size_t)tile * 128 + q];
    float l1 = plsum[(size_t)(512 + tile) * 128 + q];
    float inv = 1.0f / (l0 + l1);

    #pragma unroll
    for (int mt = 0; mt < 2; ++mt)
        #pragma unroll
        for (int m2 = 0; m2 < 4; ++m2) {
            int off = mt * 16 + m2 * 4;
            float4 a = *(const float4*)(A + off);
            float4 b = *(const float4*)(B + off);
            ushort4 h4;
            h4.x = f2bf((a.x + b.x) * inv);
            h4.y = f2bf((a.y + b.y) * inv);
            h4.z = f2bf((a.z + b.z) * inv);
            h4.w = f2bf((a.w + b.w) * inv);
            int d0 = 4 * hh + 8 * m2 + 32 * mt;
            int c  = (d0 >> 3) ^ (q & 7);
            *(ushort4*)(smem + q * 128 + c * 16 + (d0 & 7) * 2) = h4;
        }
    __syncthreads();
    #pragma unroll
    for (int it = 0; it < 4; ++it) {
        int slot = it * 256 + t;
        int row  = slot >> 3;
        int p    = slot & 7;
        uint4 v4 = *(const uint4*)(smem + row * 128 + ((p ^ (row & 7)) * 16));
        *(uint4*)&ctxb[((size_t)(bhg >> 4) * SEQ + q0 + row) * HIDDEN
                       + (bhg & 15) * HD + p * 8] = v4;
    }
}

// ---------------------------------------------------------------------------
extern "C" void kernel_launch(void* const* d_in, const int* in_sizes, int n_in,
                              void* d_out, int out_size, void* d_ws, size_t ws_size,
                              hipStream_t stream)
{
    const float* x     = (const float*)d_in[0];
    const float* w_qkv = (const float*)d_in[1];
    const float* b_qkv = (const float*)d_in[2];
    const float* w_out = (const float*)d_in[3];
    const float* b_out = (const float*)d_in[4];
    float* out = (float*)d_out;

    const size_t PH = (size_t)BATCH * HEADS * SEQ * HD;   // 4,194,304 elems/plane
    unsigned short* ws = (unsigned short*)d_ws;
    unsigned short* qB  = ws;                  // [0, PH)
    unsigned short* kB  = ws + PH;             // [PH, 2PH)
    unsigned short* vtB = ws + 2 * PH;         // [2PH, 3PH)
    unsigned short* wqh = ws + 3 * PH;         // [3PH, 3.75PH) — dead after qkv
    unsigned short* woh = wqh + 3 * PH / 4;    // [3.75PH, 4PH)
    unsigned short* cth = woh + PH / 4;        // [4PH, 6PH)  ctx bf16
    float* pacc1 = (float*)(ws + 6 * PH);      // [6PH, 8PH) = 16.8MB free tail
    float* plsum = (float*)wqh;                // 512KB in dead wqh region
    unsigned short* xh = (unsigned short*)d_out;   // x-hi in d_out (dead after qkv)
    float* pacc0 = (float*)d_out;              // partials half-0 over dead xh

    conv_hi<<<4096, 256, 0, stream>>>(x, xh);
    conv_hi<<<3072, 256, 0, stream>>>(w_qkv, wqh);
    conv_hi<<<1024, 256, 0, stream>>>(w_out, woh);
    qkv_gemm<<<dim3(32, 24), 256, 0, stream>>>(xh, wqh, b_qkv, qB, kB, vtB);
    attn_mfma<<<1024, 256, 0, stream>>>(qB, kB, vtB, pacc0, pacc1, plsum);
    attn_combine<<<512, 256, 0, stream>>>(pacc0, pacc1, plsum, cth);
    out_gemm<<<dim3(32, 8), 256, 0, stream>>>(cth, woh, b_out, out);
}

// Round 11
// 114.002 us; speedup vs baseline: 1.1392x; 1.1392x over previous
//
#include <hip/hip_runtime.h>
#include <math.h>

#define BATCH 2
#define SEQ   2048
#define HIDDEN 1024
#define HEADS 16
#define HD    64
#define QSCALE 0.18033688011112042f   // log2(e)/8 : scores computed in exp2 domain

typedef __attribute__((ext_vector_type(8)))  short short8;
typedef __attribute__((ext_vector_type(16))) float f32x16;

__device__ __forceinline__ unsigned short f2bf(float f) {
    unsigned int u = __builtin_bit_cast(unsigned int, f);
    u = (u + 0x7FFFu + ((u >> 16) & 1u)) >> 16;   // round-to-nearest-even
    return (unsigned short)u;
}
__device__ __forceinline__ float bf2f(unsigned short h) {
    unsigned int u = ((unsigned int)h) << 16;
    return __builtin_bit_cast(float, u);
}
__device__ __forceinline__ unsigned int cvt_pk_bf16(float lo, float hi) {
    unsigned int r;
    asm("v_cvt_pk_bf16_f32 %0, %1, %2" : "=v"(r) : "v"(lo), "v"(hi));
    return r;
}
__device__ __forceinline__ void gl16(const void* g, void* l) {
    __builtin_amdgcn_global_load_lds(
        (const __attribute__((address_space(1))) void*)g,
        (__attribute__((address_space(3))) void*)l,
        16, 0, 0);
}
#define WAIT_VM(N) asm volatile("s_waitcnt vmcnt(" #N ")" ::: "memory")
#define BARRIER()  do { __builtin_amdgcn_s_barrier(); __builtin_amdgcn_sched_barrier(0); } while (0)

// ---------------------------------------------------------------------------
__global__ __launch_bounds__(256)
void conv_hi(const float* __restrict__ src, unsigned short* __restrict__ hi)
{
    int idx = blockIdx.x * 256 + threadIdx.x;
    float4 v = ((const float4*)src)[idx];
    ushort4 h4;
    h4.x = f2bf(v.x); h4.y = f2bf(v.y); h4.z = f2bf(v.z); h4.w = f2bf(v.w);
    ((ushort4*)hi)[idx] = h4;
}

// ---------------------------------------------------------------------------
// Single-bf16 GEMM core, R11: 3-buffer ring (48KB, keeps 3 blocks/CU) with
// counted vmcnt — no vmcnt(0) drain at the per-iter barrier.
// Order per iter: stage(kt+1) -> WAIT_VM(4) -> BARRIER -> compute(kt).
// Read-safety: per-wave WAIT_VM(4) (8 outstanding -> oldest 4 = stage(kt))
// precedes barrier => post-barrier all waves' stage(kt) landed.
// Write-safety: stage(kt+1) issued after leaving BARRIER(kt-1) => all waves
// finished compute(kt-2), last reader of buf (kt+1)%3 (needs NB>=3).
// ---------------------------------------------------------------------------
__device__ __forceinline__ void gemm_core1(
    const char* Ah, const char* Bh,
    int m0, int n0, char* smem, f32x16 acc[2][2])
{
    const int t    = threadIdx.x;
    const int lane = t & 63;
    const int w    = t >> 6;
    const int wm   = w >> 1, wn = w & 1;
    const int l31  = lane & 31, hh = lane >> 5;

    auto stage = [&](int buf, int kt) {
        #pragma unroll
        for (int i = 0; i < 2; ++i) {
            int r  = i * 64 + (t >> 2);
            int cs = (t & 3) ^ ((r >> 1) & 3);
            gl16(Ah + ((size_t)(m0 + r) * 1024 + kt * 32 + cs * 8) * 2,
                 smem + buf * 16384 + i * 4096 + w * 1024);
            gl16(Bh + ((size_t)(n0 + r) * 1024 + kt * 32 + cs * 8) * 2,
                 smem + buf * 16384 + 8192 + i * 4096 + w * 1024);
        }
    };

    stage(0, 0);
    int cur = 0, nxt = 1;
    for (int kt = 0; kt < 32; ++kt) {
        if (kt + 1 < 32) {
            stage(nxt, kt + 1);
            WAIT_VM(4);
        } else {
            WAIT_VM(0);
        }
        BARRIER();
        const char* Ab = smem + cur * 16384;
        const char* Bb = Ab + 8192;
        #pragma unroll
        for (int ks = 0; ks < 2; ++ks) {
            short8 ah[2], bh[2];
            #pragma unroll
            for (int mt = 0; mt < 2; ++mt) {
                int R  = wm * 64 + mt * 32 + l31;
                int ch = ((ks * 2 + hh) ^ ((R >> 1) & 3)) * 16;
                ah[mt] = *(const short8*)(Ab + R * 64 + ch);
            }
            #pragma unroll
            for (int nt = 0; nt < 2; ++nt) {
                int R  = wn * 64 + nt * 32 + l31;
                int ch = ((ks * 2 + hh) ^ ((R >> 1) & 3)) * 16;
                bh[nt] = *(const short8*)(Bb + R * 64 + ch);
            }
            #pragma unroll
            for (int mt = 0; mt < 2; ++mt)
                #pragma unroll
                for (int nt = 0; nt < 2; ++nt)
                    acc[mt][nt] = __builtin_amdgcn_mfma_f32_32x32x16_bf16(ah[mt], bh[nt], acc[mt][nt], 0, 0, 0);
        }
        cur = nxt;
        nxt = (nxt == 2) ? 0 : nxt + 1;
    }
    __syncthreads();   // all waves done computing before callers reuse smem
}

// ---------------------------------------------------------------------------
// QKV GEMM + scatter epilogue via bf16 LDS stash. LDS = max(48K ring, stash).
// ---------------------------------------------------------------------------
__global__ __launch_bounds__(256, 3)
void qkv_gemm(const unsigned short* __restrict__ xh,
              const unsigned short* __restrict__ wh,
              const float* __restrict__ bias,
              unsigned short* __restrict__ qB, unsigned short* __restrict__ kB,
              unsigned short* __restrict__ vtB)
{
    __shared__ __align__(16) char smem[49152];
    f32x16 acc[2][2] = {{{}, {}}, {{}, {}}};
    const int m0 = blockIdx.x * 128, n0 = blockIdx.y * 128;
    gemm_core1((const char*)xh, (const char*)wh, m0, n0, smem, acc);

    const int t    = threadIdx.x;
    const int lane = t & 63;
    const int w    = t >> 6;
    const int wm   = w >> 1, wn = w & 1;
    const int l31  = lane & 31, hh = lane >> 5;

    const int which = n0 >> 10;            // 0=q 1=k 2=v
    const float scl = (which == 0) ? QSCALE : 1.0f;

    #pragma unroll
    for (int mt = 0; mt < 2; ++mt)
        #pragma unroll
        for (int nt = 0; nt < 2; ++nt) {
            int nl = wn * 64 + nt * 32 + l31;
            float bb = bias[n0 + nl];
            #pragma unroll
            for (int r = 0; r < 16; ++r) {
                int ml = wm * 64 + mt * 32 + (r & 3) + 8 * (r >> 2) + 4 * hh;
                float val = (acc[mt][nt][r] + bb) * scl;
                *(unsigned short*)(smem + ml * 272 + nl * 2) = f2bf(val);
            }
        }
    __syncthreads();

    const int hbase = (n0 & 1023) >> 6;
    const int b     = m0 >> 11;
    const int s0    = m0 & 2047;

    if (which < 2) {
        unsigned short* pp = which ? kB : qB;
        const int nc   = t & 31;
        const int head = hbase + (nc >> 4);
        const int d0   = (nc & 15) * 4;
        #pragma unroll
        for (int it = 0; it < 16; ++it) {
            int m = it * 8 + (t >> 5);
            ushort4 h4 = *(const ushort4*)(smem + m * 272 + nc * 8);
            size_t idx = (((size_t)(b * HEADS + head)) * SEQ + s0 + m) * HD + d0;
            *(ushort4*)&pp[idx] = h4;
        }
    } else {
        const int nl   = t & 127;
        const int head = hbase + (nl >> 6);
        const int d    = nl & 63;
        #pragma unroll
        for (int it = 0; it < 16; ++it) {
            int mq = it * 2 + (t >> 7);
            ushort4 h4;
            h4.x = *(const unsigned short*)(smem + (mq * 4 + 0) * 272 + nl * 2);
            h4.y = *(const unsigned short*)(smem + (mq * 4 + 1) * 272 + nl * 2);
            h4.z = *(const unsigned short*)(smem + (mq * 4 + 2) * 272 + nl * 2);
            h4.w = *(const unsigned short*)(smem + (mq * 4 + 3) * 272 + nl * 2);
            size_t idx = (((size_t)(b * HEADS + head)) * HD + d) * SEQ + s0 + mq * 4;
            *(ushort4*)&vtB[idx] = h4;
        }
    }
}

// ---------------------------------------------------------------------------
// Output projection GEMM, f32 epilogue.
// ---------------------------------------------------------------------------
__global__ __launch_bounds__(256, 3)
void out_gemm(const unsigned short* __restrict__ cth,
              const unsigned short* __restrict__ bh_,
              const float* __restrict__ bias, float* __restrict__ out)
{
    __shared__ __align__(16) char smem[49152];
    f32x16 acc[2][2] = {{{}, {}}, {{}, {}}};
    const int m0 = blockIdx.x * 128, n0 = blockIdx.y * 128;
    gemm_core1((const char*)cth, (const char*)bh_, m0, n0, smem, acc);

    const int t    = threadIdx.x;
    const int lane = t & 63;
    const int w    = t >> 6;
    const int wm   = w >> 1, wn = w & 1;
    const int l31  = lane & 31, hh = lane >> 5;

    #pragma unroll
    for (int mt = 0; mt < 2; ++mt)
        #pragma unroll
        for (int nt = 0; nt < 2; ++nt) {
            int n = n0 + wn * 64 + nt * 32 + l31;
            float bb = bias[n];
            #pragma unroll
            for (int r = 0; r < 16; ++r) {
                int m = m0 + wm * 64 + mt * 32 + (r & 3) + 8 * (r >> 2) + 4 * hh;
                out[(size_t)m * 1024 + n] = acc[mt][nt][r] + bb;
            }
        }
}

// ---------------------------------------------------------------------------
// Flash attention (R9-proven, reverted from split-K): max-free softmax,
// permlane P-exchange, paired K-tiles, 4-buffer ring, counted vmcnt,
// XCD swizzle, setprio, fused epilogue.
// ---------------------------------------------------------------------------
#define NPAIR (SEQ / 64)

__global__ __launch_bounds__(256, 2)
void attn_mfma(const unsigned short* __restrict__ qB, const unsigned short* __restrict__ kB,
               const unsigned short* __restrict__ vtB, unsigned short* __restrict__ ctxb)
{
    __shared__ __align__(16) char smem[65536];
    const int t    = threadIdx.x;
    const int lane = t & 63;
    const int wq   = t >> 6;
    const int l31  = lane & 31;
    const int hh   = lane >> 5;

    const int bid = blockIdx.x;
    const int xcd = bid & 7, j = bid >> 3;
    const int qt  = j & 15;
    const int bhg = xcd + 8 * (j >> 4);          // 0..31
    const int q0  = qt * 128;
    const size_t bh = (size_t)bhg;

    const char* qP = (const char*)(qB + bh * SEQ * HD);
    const char* kP = (const char*)(kB + bh * SEQ * HD);
    const char* vP = (const char*)(vtB + bh * SEQ * HD);

    const int wbase = wq * 1024;

    {   // Q: 128 rows x 128B, into [0,16K) (transient; becomes pair-buf 0)
        int rr = t >> 3, cc = t & 7;
        #pragma unroll
        for (int i = 0; i < 4; ++i) {
            int row = i * 32 + rr;
            int ch  = cc ^ (row & 7);
            gl16(qP + (size_t)(q0 + row) * 128 + ch * 16, smem + i * 4096 + wbase);
        }
    }
    // pair p -> buffer ((p+1)&3)*16384: Ka@0 Kb@4K Va@8K Vb@12K
    auto stagePair = [&](int p) {
        int base = ((p + 1) & 3) * 16384;
        int rr = t >> 3;
        int ch = (t & 7) ^ (rr & 7);
        gl16(kP + (size_t)(p * 64 + rr) * 128 + ch * 16,      smem + base +     0 + wbase);
        gl16(kP + (size_t)(p * 64 + 32 + rr) * 128 + ch * 16, smem + base +  4096 + wbase);
        int rr2 = t >> 2;
        int s4  = (rr2 & 3) ^ ((rr2 >> 2) & 3);
        int ch2 = (t & 3) ^ s4;
        gl16(vP + (size_t)rr2 * (SEQ * 2) + p * 128 +      ch2 * 16, smem + base +  8192 + wbase);
        gl16(vP + (size_t)rr2 * (SEQ * 2) + p * 128 + 64 + ch2 * 16, smem + base + 12288 + wbase);
    };
    stagePair(0);
    stagePair(1);
    WAIT_VM(8);            // Q's 4 loads (oldest) landed
    BARRIER();

    short8 qf[4];
    {
        int qrow = 32 * wq + l31;
        #pragma unroll
        for (int ks = 0; ks < 4; ++ks) {
            int ch = ((2 * ks + hh) ^ (qrow & 7)) * 16;
            qf[ks] = *(const short8*)(smem + qrow * 128 + ch);
        }
    }
    asm volatile("s_waitcnt lgkmcnt(0)" ::: "memory");   // hoist complete
    __builtin_amdgcn_sched_barrier(0);                   // before buf0 reuse

    f32x16 acc0 = {}, acc1 = {};
    float lsum = 0.0f;

    for (int i = 0; i < NPAIR; ++i) {
        if (i + 2 < NPAIR) { stagePair(i + 2); WAIT_VM(8); }
        else if (i + 1 < NPAIR) { WAIT_VM(4); }
        else { WAIT_VM(0); }
        BARRIER();

        const char* Pb = smem + ((i + 1) & 3) * 16384;

        // --- QK^T, both tiles (8 MFMA cluster) ---
        f32x16 sa = {}, sb = {};
        __builtin_amdgcn_s_setprio(1);
        #pragma unroll
        for (int ks = 0; ks < 4; ++ks) {
            int ch = ((2 * ks + hh) ^ (l31 & 7)) * 16;
            short8 ka = *(const short8*)(Pb +        l31 * 128 + ch);
            short8 kb = *(const short8*)(Pb + 4096 + l31 * 128 + ch);
            sa = __builtin_amdgcn_mfma_f32_32x32x16_bf16(ka, qf[ks], sa, 0, 0, 0);
            sb = __builtin_amdgcn_mfma_f32_32x32x16_bf16(kb, qf[ks], sb, 0, 0, 0);
        }
        __builtin_amdgcn_s_setprio(0);

        // --- exp2 direct (no max subtraction) + pack + own-half sums ---
        unsigned int pa_[8], pb_[8];
        float ps0 = 0.f, ps1 = 0.f, ps2 = 0.f, ps3 = 0.f;
        #pragma unroll
        for (int w = 0; w < 8; ++w) {
            float e0 = __builtin_amdgcn_exp2f(sa[2 * w]);
            float e1 = __builtin_amdgcn_exp2f(sa[2 * w + 1]);
            ps0 += e0; ps1 += e1;
            pa_[w] = cvt_pk_bf16(e0, e1);
            float f0 = __builtin_amdgcn_exp2f(sb[2 * w]);
            float f1 = __builtin_amdgcn_exp2f(sb[2 * w + 1]);
            ps2 += f0; ps3 += f1;
            pb_[w] = cvt_pk_bf16(f0, f1);
        }
        lsum += (ps0 + ps1) + (ps2 + ps3);

        // --- PV, both tiles; B-frags built via permlane32 half-swap ---
        const char* Va = Pb + 8192;
        const char* Vb = Pb + 12288;
        __builtin_amdgcn_s_setprio(1);
        #pragma unroll
        for (int ks = 0; ks < 2; ++ks) {
            unsigned int a0 = pa_[4*ks],     a2 = pa_[4*ks + 2];
            unsigned int a1 = pa_[4*ks + 1], a3 = pa_[4*ks + 3];
            asm volatile("v_permlane32_swap_b32 %0, %1" : "+v"(a0), "+v"(a2));
            asm volatile("v_permlane32_swap_b32 %0, %1" : "+v"(a1), "+v"(a3));
            unsigned int b0 = pb_[4*ks],     b2 = pb_[4*ks + 2];
            unsigned int b1 = pb_[4*ks + 1], b3 = pb_[4*ks + 3];
            asm volatile("v_permlane32_swap_b32 %0, %1" : "+v"(b0), "+v"(b2));
            asm volatile("v_permlane32_swap_b32 %0, %1" : "+v"(b1), "+v"(b3));
            short8 pA = __builtin_bit_cast(short8, make_uint4(a0, a1, a2, a3));
            short8 pB = __builtin_bit_cast(short8, make_uint4(b0, b1, b2, b3));
            #pragma unroll
            for (int mt = 0; mt < 2; ++mt) {
                int rrow = 32 * mt + l31;
                int s4   = (rrow & 3) ^ ((rrow >> 2) & 3);
                int ch   = ((2 * ks + hh) ^ s4) * 16;
                short8 va = *(const short8*)(Va + rrow * 64 + ch);
                short8 vb = *(const short8*)(Vb + rrow * 64 + ch);
                if (mt == 0) {
                    acc0 = __builtin_amdgcn_mfma_f32_32x32x16_bf16(va, pA, acc0, 0, 0, 0);
                    acc0 = __builtin_amdgcn_mfma_f32_32x32x16_bf16(vb, pB, acc0, 0, 0, 0);
                } else {
                    acc1 = __builtin_amdgcn_mfma_f32_32x32x16_bf16(va, pA, acc1, 0, 0, 0);
                    acc1 = __builtin_amdgcn_mfma_f32_32x32x16_bf16(vb, pB, acc1, 0, 0, 0);
                }
            }
        }
        __builtin_amdgcn_s_setprio(0);
    }

    // --- epilogue: partner-half lsum, normalize, bf16, LDS transpose ---
    lsum += __shfl_xor(lsum, 32, 64);
    __syncthreads();   // last pair's buffer occupies [0,16K) = stash region
    float inv = 1.0f / lsum;
    {
        int q = 32 * wq + l31;
        #pragma unroll
        for (int mt = 0; mt < 2; ++mt) {
            #pragma unroll
            for (int m2 = 0; m2 < 4; ++m2) {
                ushort4 h4;
                if (mt == 0) {
                    h4.x = f2bf(acc0[4*m2+0] * inv); h4.y = f2bf(acc0[4*m2+1] * inv);
                    h4.z = f2bf(acc0[4*m2+2] * inv); h4.w = f2bf(acc0[4*m2+3] * inv);
                } else {
                    h4.x = f2bf(acc1[4*m2+0] * inv); h4.y = f2bf(acc1[4*m2+1] * inv);
                    h4.z = f2bf(acc1[4*m2+2] * inv); h4.w = f2bf(acc1[4*m2+3] * inv);
                }
                int d0 = 4 * hh + 8 * m2 + 32 * mt;
                int c  = (d0 >> 3) ^ (q & 7);
                *(ushort4*)(smem + q * 128 + c * 16 + (d0 & 7) * 2) = h4;
            }
        }
    }
    __syncthreads();
    {
        #pragma unroll
        for (int it = 0; it < 4; ++it) {
            int slot = it * 256 + t;
            int row  = slot >> 3;
            int p    = slot & 7;
            uint4 v4 = *(const uint4*)(smem + row * 128 + ((p ^ (row & 7)) * 16));
            *(uint4*)&ctxb[((size_t)(bhg >> 4) * SEQ + q0 + row) * HIDDEN
                           + (bhg & 15) * HD + p * 8] = v4;
        }
    }
}

// ---------------------------------------------------------------------------
extern "C" void kernel_launch(void* const* d_in, const int* in_sizes, int n_in,
                              void* d_out, int out_size, void* d_ws, size_t ws_size,
                              hipStream_t stream)
{
    const float* x     = (const float*)d_in[0];
    const float* w_qkv = (const float*)d_in[1];
    const float* b_qkv = (const float*)d_in[2];
    const float* w_out = (const float*)d_in[3];
    const float* b_out = (const float*)d_in[4];
    float* out = (float*)d_out;

    const size_t PH = (size_t)BATCH * HEADS * SEQ * HD;   // 4,194,304 elems/plane
    unsigned short* ws = (unsigned short*)d_ws;
    unsigned short* qB  = ws;                  // [0, PH)
    unsigned short* kB  = ws + PH;             // [PH, 2PH)
    unsigned short* vtB = ws + 2 * PH;         // [2PH, 3PH)
    unsigned short* wqh = ws + 3 * PH;         // [3PH, 3.75PH)
    unsigned short* woh = wqh + 3 * PH / 4;    // [3.75PH, 4PH)
    unsigned short* cth = woh + PH / 4;        // [4PH, 6PH)  ctx bf16
    unsigned short* xh  = (unsigned short*)d_out;  // x-hi lives in d_out

    conv_hi<<<4096, 256, 0, stream>>>(x, xh);
    conv_hi<<<3072, 256, 0, stream>>>(w_qkv, wqh);
    conv_hi<<<1024, 256, 0, stream>>>(w_out, woh);
    qkv_gemm<<<dim3(32, 24), 256, 0, stream>>>(xh, wqh, b_qkv, qB, kB, vtB);
    attn_mfma<<<512, 256, 0, stream>>>(qB, kB, vtB, cth);
    out_gemm<<<dim3(32, 8), 256, 0, stream>>>(cth, woh, b_out, out);
}

// Round 12
// 110.638 us; speedup vs baseline: 1.1738x; 1.0304x over previous
//
#include <hip/hip_runtime.h>
#include <math.h>

#define BATCH 2
#define SEQ   2048
#define HIDDEN 1024
#define HEADS 16
#define HD    64
#define QSCALE 0.18033688011112042f   // log2(e)/8 : scores computed in exp2 domain

typedef __attribute__((ext_vector_type(8)))  short short8;
typedef __attribute__((ext_vector_type(16))) float f32x16;

__device__ __forceinline__ unsigned short f2bf(float f) {
    unsigned int u = __builtin_bit_cast(unsigned int, f);
    u = (u + 0x7FFFu + ((u >> 16) & 1u)) >> 16;   // round-to-nearest-even
    return (unsigned short)u;
}
__device__ __forceinline__ unsigned int cvt_pk_bf16(float lo, float hi) {
    unsigned int r;
    asm("v_cvt_pk_bf16_f32 %0, %1, %2" : "=v"(r) : "v"(lo), "v"(hi));
    return r;
}
__device__ __forceinline__ void gl16(const void* g, void* l) {
    __builtin_amdgcn_global_load_lds(
        (const __attribute__((address_space(1))) void*)g,
        (__attribute__((address_space(3))) void*)l,
        16, 0, 0);
}
#define WAIT_VM(N) asm volatile("s_waitcnt vmcnt(" #N ")" ::: "memory")
#define BARRIER()  do { __builtin_amdgcn_s_barrier(); __builtin_amdgcn_sched_barrier(0); } while (0)

// ---------------------------------------------------------------------------
// Merged conversion: one launch converts x, w_qkv, w_out to bf16-hi planes.
// ---------------------------------------------------------------------------
__global__ __launch_bounds__(256)
void conv_all(const float* __restrict__ x,  unsigned short* __restrict__ xh,
              const float* __restrict__ wq, unsigned short* __restrict__ wqh,
              const float* __restrict__ wo, unsigned short* __restrict__ woh)
{
    int b = blockIdx.x;
    const float* src;
    unsigned short* dst;
    int base;
    if (b < 4096)      { src = x;  dst = xh;  base = b; }
    else if (b < 7168) { src = wq; dst = wqh; base = b - 4096; }
    else               { src = wo; dst = woh; base = b - 7168; }
    int idx = base * 256 + threadIdx.x;
    float4 v = ((const float4*)src)[idx];
    ushort4 h4;
    h4.x = f2bf(v.x); h4.y = f2bf(v.y); h4.z = f2bf(v.z); h4.w = f2bf(v.w);
    ((ushort4*)dst)[idx] = h4;
}

// ---------------------------------------------------------------------------
// Single-bf16 GEMM core (R11-frozen): 3-buffer ring, counted vmcnt.
// ---------------------------------------------------------------------------
__device__ __forceinline__ void gemm_core1(
    const char* Ah, const char* Bh,
    int m0, int n0, char* smem, f32x16 acc[2][2])
{
    const int t    = threadIdx.x;
    const int lane = t & 63;
    const int w    = t >> 6;
    const int wm   = w >> 1, wn = w & 1;
    const int l31  = lane & 31, hh = lane >> 5;

    auto stage = [&](int buf, int kt) {
        #pragma unroll
        for (int i = 0; i < 2; ++i) {
            int r  = i * 64 + (t >> 2);
            int cs = (t & 3) ^ ((r >> 1) & 3);
            gl16(Ah + ((size_t)(m0 + r) * 1024 + kt * 32 + cs * 8) * 2,
                 smem + buf * 16384 + i * 4096 + w * 1024);
            gl16(Bh + ((size_t)(n0 + r) * 1024 + kt * 32 + cs * 8) * 2,
                 smem + buf * 16384 + 8192 + i * 4096 + w * 1024);
        }
    };

    stage(0, 0);
    int cur = 0, nxt = 1;
    for (int kt = 0; kt < 32; ++kt) {
        if (kt + 1 < 32) {
            stage(nxt, kt + 1);
            WAIT_VM(4);
        } else {
            WAIT_VM(0);
        }
        BARRIER();
        const char* Ab = smem + cur * 16384;
        const char* Bb = Ab + 8192;
        #pragma unroll
        for (int ks = 0; ks < 2; ++ks) {
            short8 ah[2], bh[2];
            #pragma unroll
            for (int mt = 0; mt < 2; ++mt) {
                int R  = wm * 64 + mt * 32 + l31;
                int ch = ((ks * 2 + hh) ^ ((R >> 1) & 3)) * 16;
                ah[mt] = *(const short8*)(Ab + R * 64 + ch);
            }
            #pragma unroll
            for (int nt = 0; nt < 2; ++nt) {
                int R  = wn * 64 + nt * 32 + l31;
                int ch = ((ks * 2 + hh) ^ ((R >> 1) & 3)) * 16;
                bh[nt] = *(const short8*)(Bb + R * 64 + ch);
            }
            #pragma unroll
            for (int mt = 0; mt < 2; ++mt)
                #pragma unroll
                for (int nt = 0; nt < 2; ++nt)
                    acc[mt][nt] = __builtin_amdgcn_mfma_f32_32x32x16_bf16(ah[mt], bh[nt], acc[mt][nt], 0, 0, 0);
        }
        cur = nxt;
        nxt = (nxt == 2) ? 0 : nxt + 1;
    }
    __syncthreads();
}

// ---------------------------------------------------------------------------
// QKV GEMM (frozen).
// ---------------------------------------------------------------------------
__global__ __launch_bounds__(256, 3)
void qkv_gemm(const unsigned short* __restrict__ xh,
              const unsigned short* __restrict__ wh,
              const float* __restrict__ bias,
              unsigned short* __restrict__ qB, unsigned short* __restrict__ kB,
              unsigned short* __restrict__ vtB)
{
    __shared__ __align__(16) char smem[49152];
    f32x16 acc[2][2] = {{{}, {}}, {{}, {}}};
    const int m0 = blockIdx.x * 128, n0 = blockIdx.y * 128;
    gemm_core1((const char*)xh, (const char*)wh, m0, n0, smem, acc);

    const int t    = threadIdx.x;
    const int lane = t & 63;
    const int w    = t >> 6;
    const int wm   = w >> 1, wn = w & 1;
    const int l31  = lane & 31, hh = lane >> 5;

    const int which = n0 >> 10;            // 0=q 1=k 2=v
    const float scl = (which == 0) ? QSCALE : 1.0f;

    #pragma unroll
    for (int mt = 0; mt < 2; ++mt)
        #pragma unroll
        for (int nt = 0; nt < 2; ++nt) {
            int nl = wn * 64 + nt * 32 + l31;
            float bb = bias[n0 + nl];
            #pragma unroll
            for (int r = 0; r < 16; ++r) {
                int ml = wm * 64 + mt * 32 + (r & 3) + 8 * (r >> 2) + 4 * hh;
                float val = (acc[mt][nt][r] + bb) * scl;
                *(unsigned short*)(smem + ml * 272 + nl * 2) = f2bf(val);
            }
        }
    __syncthreads();

    const int hbase = (n0 & 1023) >> 6;
    const int b     = m0 >> 11;
    const int s0    = m0 & 2047;

    if (which < 2) {
        unsigned short* pp = which ? kB : qB;
        const int nc   = t & 31;
        const int head = hbase + (nc >> 4);
        const int d0   = (nc & 15) * 4;
        #pragma unroll
        for (int it = 0; it < 16; ++it) {
            int m = it * 8 + (t >> 5);
            ushort4 h4 = *(const ushort4*)(smem + m * 272 + nc * 8);
            size_t idx = (((size_t)(b * HEADS + head)) * SEQ + s0 + m) * HD + d0;
            *(ushort4*)&pp[idx] = h4;
        }
    } else {
        const int nl   = t & 127;
        const int head = hbase + (nl >> 6);
        const int d    = nl & 63;
        #pragma unroll
        for (int it = 0; it < 16; ++it) {
            int mq = it * 2 + (t >> 7);
            ushort4 h4;
            h4.x = *(const unsigned short*)(smem + (mq * 4 + 0) * 272 + nl * 2);
            h4.y = *(const unsigned short*)(smem + (mq * 4 + 1) * 272 + nl * 2);
            h4.z = *(const unsigned short*)(smem + (mq * 4 + 2) * 272 + nl * 2);
            h4.w = *(const unsigned short*)(smem + (mq * 4 + 3) * 272 + nl * 2);
            size_t idx = (((size_t)(b * HEADS + head)) * HD + d) * SEQ + s0 + mq * 4;
            *(ushort4*)&vtB[idx] = h4;
        }
    }
}

// ---------------------------------------------------------------------------
// Output projection GEMM (frozen).
// ---------------------------------------------------------------------------
__global__ __launch_bounds__(256, 3)
void out_gemm(const unsigned short* __restrict__ cth,
              const unsigned short* __restrict__ bh_,
              const float* __restrict__ bias, float* __restrict__ out)
{
    __shared__ __align__(16) char smem[49152];
    f32x16 acc[2][2] = {{{}, {}}, {{}, {}}};
    const int m0 = blockIdx.x * 128, n0 = blockIdx.y * 128;
    gemm_core1((const char*)cth, (const char*)bh_, m0, n0, smem, acc);

    const int t    = threadIdx.x;
    const int lane = t & 63;
    const int w    = t >> 6;
    const int wm   = w >> 1, wn = w & 1;
    const int l31  = lane & 31, hh = lane >> 5;

    #pragma unroll
    for (int mt = 0; mt < 2; ++mt)
        #pragma unroll
        for (int nt = 0; nt < 2; ++nt) {
            int n = n0 + wn * 64 + nt * 32 + l31;
            float bb = bias[n];
            #pragma unroll
            for (int r = 0; r < 16; ++r) {
                int m = m0 + wm * 64 + mt * 32 + (r & 3) + 8 * (r >> 2) + 4 * hh;
                out[(size_t)m * 1024 + n] = acc[mt][nt][r] + bb;
            }
        }
}

// ---------------------------------------------------------------------------
// Flash attention R12: early-QK software pipeline. Per iter i:
//   stage(i+2) -> WAIT_VM(4) -> BARRIER -> QK(i+1) [MFMA, no dep on SM(i)]
//   -> SM(i) [VALU overlaps QK(i+1) completion] -> PV(i).
// Ledger: QK(i+1) reads buf((i+2)&3) K (staged iter i-1, drained by this
// WAIT_VM(4)+barrier); stage(i+2) writes buf((i+3)&3), last read by
// PV(i-2)/QK(i-2) which all waves finished before BARRIER(i-1). 4-buf ring.
// Numerics identical to R9/R11 (same ops, same order).
// ---------------------------------------------------------------------------
#define NPAIR (SEQ / 64)

__global__ __launch_bounds__(256, 2)
void attn_mfma(const unsigned short* __restrict__ qB, const unsigned short* __restrict__ kB,
               const unsigned short* __restrict__ vtB, unsigned short* __restrict__ ctxb)
{
    __shared__ __align__(16) char smem[65536];
    const int t    = threadIdx.x;
    const int lane = t & 63;
    const int wq   = t >> 6;
    const int l31  = lane & 31;
    const int hh   = lane >> 5;

    const int bid = blockIdx.x;
    const int xcd = bid & 7, j = bid >> 3;
    const int qt  = j & 15;
    const int bhg = xcd + 8 * (j >> 4);          // 0..31
    const int q0  = qt * 128;
    const size_t bh = (size_t)bhg;

    const char* qP = (const char*)(qB + bh * SEQ * HD);
    const char* kP = (const char*)(kB + bh * SEQ * HD);
    const char* vP = (const char*)(vtB + bh * SEQ * HD);

    const int wbase = wq * 1024;

    {   // Q: 128 rows x 128B, into [0,16K) (transient; becomes pair-buf 0)
        int rr = t >> 3, cc = t & 7;
        #pragma unroll
        for (int i = 0; i < 4; ++i) {
            int row = i * 32 + rr;
            int ch  = cc ^ (row & 7);
            gl16(qP + (size_t)(q0 + row) * 128 + ch * 16, smem + i * 4096 + wbase);
        }
    }
    // pair p -> buffer ((p+1)&3)*16384: Ka@0 Kb@4K Va@8K Vb@12K
    auto stagePair = [&](int p) {
        int base = ((p + 1) & 3) * 16384;
        int rr = t >> 3;
        int ch = (t & 7) ^ (rr & 7);
        gl16(kP + (size_t)(p * 64 + rr) * 128 + ch * 16,      smem + base +     0 + wbase);
        gl16(kP + (size_t)(p * 64 + 32 + rr) * 128 + ch * 16, smem + base +  4096 + wbase);
        int rr2 = t >> 2;
        int s4  = (rr2 & 3) ^ ((rr2 >> 2) & 3);
        int ch2 = (t & 3) ^ s4;
        gl16(vP + (size_t)rr2 * (SEQ * 2) + p * 128 +      ch2 * 16, smem + base +  8192 + wbase);
        gl16(vP + (size_t)rr2 * (SEQ * 2) + p * 128 + 64 + ch2 * 16, smem + base + 12288 + wbase);
    };
    stagePair(0);
    stagePair(1);
    WAIT_VM(8);            // Q's 4 loads (oldest) landed
    BARRIER();

    short8 qf[4];
    {
        int qrow = 32 * wq + l31;
        #pragma unroll
        for (int ks = 0; ks < 4; ++ks) {
            int ch = ((2 * ks + hh) ^ (qrow & 7)) * 16;
            qf[ks] = *(const short8*)(smem + qrow * 128 + ch);
        }
    }
    asm volatile("s_waitcnt lgkmcnt(0)" ::: "memory");   // hoist complete
    __builtin_amdgcn_sched_barrier(0);
    WAIT_VM(4);            // pair-0 K/V landed (own loads)
    BARRIER();             // ... and all other waves' too; hoists done

    // --- prologue QK(0) ---
    f32x16 sa = {}, sb = {};
    {
        const char* Pb = smem + 16384;   // buf1 = pair 0
        __builtin_amdgcn_s_setprio(1);
        #pragma unroll
        for (int ks = 0; ks < 4; ++ks) {
            int ch = ((2 * ks + hh) ^ (l31 & 7)) * 16;
            short8 ka = *(const short8*)(Pb +        l31 * 128 + ch);
            short8 kb = *(const short8*)(Pb + 4096 + l31 * 128 + ch);
            sa = __builtin_amdgcn_mfma_f32_32x32x16_bf16(ka, qf[ks], sa, 0, 0, 0);
            sb = __builtin_amdgcn_mfma_f32_32x32x16_bf16(kb, qf[ks], sb, 0, 0, 0);
        }
        __builtin_amdgcn_s_setprio(0);
    }

    f32x16 acc0 = {}, acc1 = {};
    float lsum = 0.0f;

    for (int i = 0; i < NPAIR; ++i) {
        if (i + 2 < NPAIR) { stagePair(i + 2); WAIT_VM(4); }
        else if (i + 1 < NPAIR) { WAIT_VM(0); }
        BARRIER();

        // --- early QK(i+1): no dependency on SM(i); MFMA latency hides
        //     under the exp/pack VALU below ---
        f32x16 na = {}, nb = {};
        if (i + 1 < NPAIR) {
            const char* Pn = smem + ((i + 2) & 3) * 16384;
            __builtin_amdgcn_s_setprio(1);
            #pragma unroll
            for (int ks = 0; ks < 4; ++ks) {
                int ch = ((2 * ks + hh) ^ (l31 & 7)) * 16;
                short8 ka = *(const short8*)(Pn +        l31 * 128 + ch);
                short8 kb = *(const short8*)(Pn + 4096 + l31 * 128 + ch);
                na = __builtin_amdgcn_mfma_f32_32x32x16_bf16(ka, qf[ks], na, 0, 0, 0);
                nb = __builtin_amdgcn_mfma_f32_32x32x16_bf16(kb, qf[ks], nb, 0, 0, 0);
            }
            __builtin_amdgcn_s_setprio(0);
        }

        // --- SM(i): exp2 direct + pack + own-half sums ---
        unsigned int pa_[8], pb_[8];
        float ps0 = 0.f, ps1 = 0.f, ps2 = 0.f, ps3 = 0.f;
        #pragma unroll
        for (int w = 0; w < 8; ++w) {
            float e0 = __builtin_amdgcn_exp2f(sa[2 * w]);
            float e1 = __builtin_amdgcn_exp2f(sa[2 * w + 1]);
            ps0 += e0; ps1 += e1;
            pa_[w] = cvt_pk_bf16(e0, e1);
            float f0 = __builtin_amdgcn_exp2f(sb[2 * w]);
            float f1 = __builtin_amdgcn_exp2f(sb[2 * w + 1]);
            ps2 += f0; ps3 += f1;
            pb_[w] = cvt_pk_bf16(f0, f1);
        }
        lsum += (ps0 + ps1) + (ps2 + ps3);

        // --- PV(i); B-frags via permlane32 half-swap ---
        const char* Pb = smem + ((i + 1) & 3) * 16384;
        const char* Va = Pb + 8192;
        const char* Vb = Pb + 12288;
        __builtin_amdgcn_s_setprio(1);
        #pragma unroll
        for (int ks = 0; ks < 2; ++ks) {
            unsigned int a0 = pa_[4*ks],     a2 = pa_[4*ks + 2];
            unsigned int a1 = pa_[4*ks + 1], a3 = pa_[4*ks + 3];
            asm volatile("v_permlane32_swap_b32 %0, %1" : "+v"(a0), "+v"(a2));
            asm volatile("v_permlane32_swap_b32 %0, %1" : "+v"(a1), "+v"(a3));
            unsigned int b0 = pb_[4*ks],     b2 = pb_[4*ks + 2];
            unsigned int b1 = pb_[4*ks + 1], b3 = pb_[4*ks + 3];
            asm volatile("v_permlane32_swap_b32 %0, %1" : "+v"(b0), "+v"(b2));
            asm volatile("v_permlane32_swap_b32 %0, %1" : "+v"(b1), "+v"(b3));
            short8 pA = __builtin_bit_cast(short8, make_uint4(a0, a1, a2, a3));
            short8 pB = __builtin_bit_cast(short8, make_uint4(b0, b1, b2, b3));
            #pragma unroll
            for (int mt = 0; mt < 2; ++mt) {
                int rrow = 32 * mt + l31;
                int s4   = (rrow & 3) ^ ((rrow >> 2) & 3);
                int ch   = ((2 * ks + hh) ^ s4) * 16;
                short8 va = *(const short8*)(Va + rrow * 64 + ch);
                short8 vb = *(const short8*)(Vb + rrow * 64 + ch);
                if (mt == 0) {
                    acc0 = __builtin_amdgcn_mfma_f32_32x32x16_bf16(va, pA, acc0, 0, 0, 0);
                    acc0 = __builtin_amdgcn_mfma_f32_32x32x16_bf16(vb, pB, acc0, 0, 0, 0);
                } else {
                    acc1 = __builtin_amdgcn_mfma_f32_32x32x16_bf16(va, pA, acc1, 0, 0, 0);
                    acc1 = __builtin_amdgcn_mfma_f32_32x32x16_bf16(vb, pB, acc1, 0, 0, 0);
                }
            }
        }
        __builtin_amdgcn_s_setprio(0);

        sa = na; sb = nb;
    }

    // --- epilogue: partner-half lsum, normalize, bf16, LDS transpose ---
    lsum += __shfl_xor(lsum, 32, 64);
    __syncthreads();   // last pair's buffer occupies [0,16K) = stash region
    float inv = 1.0f / lsum;
    {
        int q = 32 * wq + l31;
        #pragma unroll
        for (int mt = 0; mt < 2; ++mt) {
            #pragma unroll
            for (int m2 = 0; m2 < 4; ++m2) {
                ushort4 h4;
                if (mt == 0) {
                    h4.x = f2bf(acc0[4*m2+0] * inv); h4.y = f2bf(acc0[4*m2+1] * inv);
                    h4.z = f2bf(acc0[4*m2+2] * inv); h4.w = f2bf(acc0[4*m2+3] * inv);
                } else {
                    h4.x = f2bf(acc1[4*m2+0] * inv); h4.y = f2bf(acc1[4*m2+1] * inv);
                    h4.z = f2bf(acc1[4*m2+2] * inv); h4.w = f2bf(acc1[4*m2+3] * inv);
                }
                int d0 = 4 * hh + 8 * m2 + 32 * mt;
                int c  = (d0 >> 3) ^ (q & 7);
                *(ushort4*)(smem + q * 128 + c * 16 + (d0 & 7) * 2) = h4;
            }
        }
    }
    __syncthreads();
    {
        #pragma unroll
        for (int it = 0; it < 4; ++it) {
            int slot = it * 256 + t;
            int row  = slot >> 3;
            int p    = slot & 7;
            uint4 v4 = *(const uint4*)(smem + row * 128 + ((p ^ (row & 7)) * 16));
            *(uint4*)&ctxb[((size_t)(bhg >> 4) * SEQ + q0 + row) * HIDDEN
                           + (bhg & 15) * HD + p * 8] = v4;
        }
    }
}

// ---------------------------------------------------------------------------
extern "C" void kernel_launch(void* const* d_in, const int* in_sizes, int n_in,
                              void* d_out, int out_size, void* d_ws, size_t ws_size,
                              hipStream_t stream)
{
    const float* x     = (const float*)d_in[0];
    const float* w_qkv = (const float*)d_in[1];
    const float* b_qkv = (const float*)d_in[2];
    const float* w_out = (const float*)d_in[3];
    const float* b_out = (const float*)d_in[4];
    float* out = (float*)d_out;

    const size_t PH = (size_t)BATCH * HEADS * SEQ * HD;   // 4,194,304 elems/plane
    unsigned short* ws = (unsigned short*)d_ws;
    unsigned short* qB  = ws;                  // [0, PH)
    unsigned short* kB  = ws + PH;             // [PH, 2PH)
    unsigned short* vtB = ws + 2 * PH;         // [2PH, 3PH)
    unsigned short* wqh = ws + 3 * PH;         // [3PH, 3.75PH)
    unsigned short* woh = wqh + 3 * PH / 4;    // [3.75PH, 4PH)
    unsigned short* cth = woh + PH / 4;        // [4PH, 6PH)  ctx bf16
    unsigned short* xh  = (unsigned short*)d_out;  // x-hi lives in d_out

    conv_all<<<8192, 256, 0, stream>>>(x, xh, w_qkv, wqh, w_out, woh);
    qkv_gemm<<<dim3(32, 24), 256, 0, stream>>>(xh, wqh, b_qkv, qB, kB, vtB);
    attn_mfma<<<512, 256, 0, stream>>>(qB, kB, vtB, cth);
    out_gemm<<<dim3(32, 8), 256, 0, stream>>>(cth, woh, b_out, out);
}

// Round 13
// 107.678 us; speedup vs baseline: 1.2061x; 1.0275x over previous
//
#include <hip/hip_runtime.h>
#include <math.h>

#define BATCH 2
#define SEQ   2048
#define HIDDEN 1024
#define HEADS 16
#define HD    64
#define QSCALE 0.18033688011112042f   // log2(e)/8 : scores computed in exp2 domain

typedef __attribute__((ext_vector_type(8)))  short short8;
typedef __attribute__((ext_vector_type(16))) float f32x16;

__device__ __forceinline__ unsigned short f2bf(float f) {
    unsigned int u = __builtin_bit_cast(unsigned int, f);
    u = (u + 0x7FFFu + ((u >> 16) & 1u)) >> 16;   // round-to-nearest-even
    return (unsigned short)u;
}
__device__ __forceinline__ unsigned int cvt_pk_bf16(float lo, float hi) {
    unsigned int r;
    asm("v_cvt_pk_bf16_f32 %0, %1, %2" : "=v"(r) : "v"(lo), "v"(hi));
    return r;
}
__device__ __forceinline__ void gl16(const void* g, void* l) {
    __builtin_amdgcn_global_load_lds(
        (const __attribute__((address_space(1))) void*)g,
        (__attribute__((address_space(3))) void*)l,
        16, 0, 0);
}
#define WAIT_VM(N) asm volatile("s_waitcnt vmcnt(" #N ")" ::: "memory")
#define BARRIER()  do { __builtin_amdgcn_s_barrier(); __builtin_amdgcn_sched_barrier(0); } while (0)

// ---------------------------------------------------------------------------
// Merged conversion (frozen).
// ---------------------------------------------------------------------------
__global__ __launch_bounds__(256)
void conv_all(const float* __restrict__ x,  unsigned short* __restrict__ xh,
              const float* __restrict__ wq, unsigned short* __restrict__ wqh,
              const float* __restrict__ wo, unsigned short* __restrict__ woh)
{
    int b = blockIdx.x;
    const float* src;
    unsigned short* dst;
    int base;
    if (b < 4096)      { src = x;  dst = xh;  base = b; }
    else if (b < 7168) { src = wq; dst = wqh; base = b - 4096; }
    else               { src = wo; dst = woh; base = b - 7168; }
    int idx = base * 256 + threadIdx.x;
    float4 v = ((const float4*)src)[idx];
    ushort4 h4;
    h4.x = f2bf(v.x); h4.y = f2bf(v.y); h4.z = f2bf(v.z); h4.w = f2bf(v.w);
    ((ushort4*)dst)[idx] = h4;
}

// ---------------------------------------------------------------------------
// Single-bf16 GEMM core (R11-frozen): 3-buffer ring, counted vmcnt.
// ---------------------------------------------------------------------------
__device__ __forceinline__ void gemm_core1(
    const char* Ah, const char* Bh,
    int m0, int n0, char* smem, f32x16 acc[2][2])
{
    const int t    = threadIdx.x;
    const int lane = t & 63;
    const int w    = t >> 6;
    const int wm   = w >> 1, wn = w & 1;
    const int l31  = lane & 31, hh = lane >> 5;

    auto stage = [&](int buf, int kt) {
        #pragma unroll
        for (int i = 0; i < 2; ++i) {
            int r  = i * 64 + (t >> 2);
            int cs = (t & 3) ^ ((r >> 1) & 3);
            gl16(Ah + ((size_t)(m0 + r) * 1024 + kt * 32 + cs * 8) * 2,
                 smem + buf * 16384 + i * 4096 + w * 1024);
            gl16(Bh + ((size_t)(n0 + r) * 1024 + kt * 32 + cs * 8) * 2,
                 smem + buf * 16384 + 8192 + i * 4096 + w * 1024);
        }
    };

    stage(0, 0);
    int cur = 0, nxt = 1;
    for (int kt = 0; kt < 32; ++kt) {
        if (kt + 1 < 32) {
            stage(nxt, kt + 1);
            WAIT_VM(4);
        } else {
            WAIT_VM(0);
        }
        BARRIER();
        const char* Ab = smem + cur * 16384;
        const char* Bb = Ab + 8192;
        #pragma unroll
        for (int ks = 0; ks < 2; ++ks) {
            short8 ah[2], bh[2];
            #pragma unroll
            for (int mt = 0; mt < 2; ++mt) {
                int R  = wm * 64 + mt * 32 + l31;
                int ch = ((ks * 2 + hh) ^ ((R >> 1) & 3)) * 16;
                ah[mt] = *(const short8*)(Ab + R * 64 + ch);
            }
            #pragma unroll
            for (int nt = 0; nt < 2; ++nt) {
                int R  = wn * 64 + nt * 32 + l31;
                int ch = ((ks * 2 + hh) ^ ((R >> 1) & 3)) * 16;
                bh[nt] = *(const short8*)(Bb + R * 64 + ch);
            }
            #pragma unroll
            for (int mt = 0; mt < 2; ++mt)
                #pragma unroll
                for (int nt = 0; nt < 2; ++nt)
                    acc[mt][nt] = __builtin_amdgcn_mfma_f32_32x32x16_bf16(ah[mt], bh[nt], acc[mt][nt], 0, 0, 0);
        }
        cur = nxt;
        nxt = (nxt == 2) ? 0 : nxt + 1;
    }
    __syncthreads();
}

// ---------------------------------------------------------------------------
// QKV GEMM (frozen).
// ---------------------------------------------------------------------------
__global__ __launch_bounds__(256, 3)
void qkv_gemm(const unsigned short* __restrict__ xh,
              const unsigned short* __restrict__ wh,
              const float* __restrict__ bias,
              unsigned short* __restrict__ qB, unsigned short* __restrict__ kB,
              unsigned short* __restrict__ vtB)
{
    __shared__ __align__(16) char smem[49152];
    f32x16 acc[2][2] = {{{}, {}}, {{}, {}}};
    const int m0 = blockIdx.x * 128, n0 = blockIdx.y * 128;
    gemm_core1((const char*)xh, (const char*)wh, m0, n0, smem, acc);

    const int t    = threadIdx.x;
    const int lane = t & 63;
    const int w    = t >> 6;
    const int wm   = w >> 1, wn = w & 1;
    const int l31  = lane & 31, hh = lane >> 5;

    const int which = n0 >> 10;            // 0=q 1=k 2=v
    const float scl = (which == 0) ? QSCALE : 1.0f;

    #pragma unroll
    for (int mt = 0; mt < 2; ++mt)
        #pragma unroll
        for (int nt = 0; nt < 2; ++nt) {
            int nl = wn * 64 + nt * 32 + l31;
            float bb = bias[n0 + nl];
            #pragma unroll
            for (int r = 0; r < 16; ++r) {
                int ml = wm * 64 + mt * 32 + (r & 3) + 8 * (r >> 2) + 4 * hh;
                float val = (acc[mt][nt][r] + bb) * scl;
                *(unsigned short*)(smem + ml * 272 + nl * 2) = f2bf(val);
            }
        }
    __syncthreads();

    const int hbase = (n0 & 1023) >> 6;
    const int b     = m0 >> 11;
    const int s0    = m0 & 2047;

    if (which < 2) {
        unsigned short* pp = which ? kB : qB;
        const int nc   = t & 31;
        const int head = hbase + (nc >> 4);
        const int d0   = (nc & 15) * 4;
        #pragma unroll
        for (int it = 0; it < 16; ++it) {
            int m = it * 8 + (t >> 5);
            ushort4 h4 = *(const ushort4*)(smem + m * 272 + nc * 8);
            size_t idx = (((size_t)(b * HEADS + head)) * SEQ + s0 + m) * HD + d0;
            *(ushort4*)&pp[idx] = h4;
        }
    } else {
        const int nl   = t & 127;
        const int head = hbase + (nl >> 6);
        const int d    = nl & 63;
        #pragma unroll
        for (int it = 0; it < 16; ++it) {
            int mq = it * 2 + (t >> 7);
            ushort4 h4;
            h4.x = *(const unsigned short*)(smem + (mq * 4 + 0) * 272 + nl * 2);
            h4.y = *(const unsigned short*)(smem + (mq * 4 + 1) * 272 + nl * 2);
            h4.z = *(const unsigned short*)(smem + (mq * 4 + 2) * 272 + nl * 2);
            h4.w = *(const unsigned short*)(smem + (mq * 4 + 3) * 272 + nl * 2);
            size_t idx = (((size_t)(b * HEADS + head)) * HD + d) * SEQ + s0 + mq * 4;
            *(ushort4*)&vtB[idx] = h4;
        }
    }
}

// ---------------------------------------------------------------------------
// Output projection GEMM (frozen).
// ---------------------------------------------------------------------------
__global__ __launch_bounds__(256, 3)
void out_gemm(const unsigned short* __restrict__ cth,
              const unsigned short* __restrict__ bh_,
              const float* __restrict__ bias, float* __restrict__ out)
{
    __shared__ __align__(16) char smem[49152];
    f32x16 acc[2][2] = {{{}, {}}, {{}, {}}};
    const int m0 = blockIdx.x * 128, n0 = blockIdx.y * 128;
    gemm_core1((const char*)cth, (const char*)bh_, m0, n0, smem, acc);

    const int t    = threadIdx.x;
    const int lane = t & 63;
    const int w    = t >> 6;
    const int wm   = w >> 1, wn = w & 1;
    const int l31  = lane & 31, hh = lane >> 5;

    #pragma unroll
    for (int mt = 0; mt < 2; ++mt)
        #pragma unroll
        for (int nt = 0; nt < 2; ++nt) {
            int n = n0 + wn * 64 + nt * 32 + l31;
            float bb = bias[n];
            #pragma unroll
            for (int r = 0; r < 16; ++r) {
                int m = m0 + wm * 64 + mt * 32 + (r & 3) + 8 * (r >> 2) + 4 * hh;
                out[(size_t)m * 1024 + n] = acc[mt][nt][r] + bb;
            }
        }
}

// ---------------------------------------------------------------------------
// Flash attention R13: in-block split-K. 512 threads = 8 waves = 2 groups.
// Group g owns K-pairs [g*16, g*16+16), own 2-buffer ring at g*32KB, classic
// 2-barrier iter: stage(i+1)->WAIT_VM(4)->BARRIER->compute(i)->BARRIER
// (tail barrier makes 2-buf reuse safe: buf (i+1)&1's last reader compute(i-1)
// finished before it). Max-free softmax => partials are exact plain sums;
// group1 dumps acc lane-major to LDS, group0 merges + epilogue.
// Q parks in ring1-buf1 [49152,65536), hoisted+fenced before iter0 stages it.
// LDS 64.5KB -> 2 blocks/CU = 16 waves/CU = 4 waves/SIMD (was 2).
// ---------------------------------------------------------------------------
#define NPAIR (SEQ / 64)

__global__ __launch_bounds__(512, 4)
void attn_mfma(const unsigned short* __restrict__ qB, const unsigned short* __restrict__ kB,
               const unsigned short* __restrict__ vtB, unsigned short* __restrict__ ctxb)
{
    __shared__ __align__(16) char smem[66048];   // 2x32KB rings + 512B lsum
    const int t    = threadIdx.x;
    const int lane = t & 63;
    const int wq   = t >> 6;          // 0..7
    const int grp  = wq >> 2;         // K-split group
    const int wql  = wq & 3;          // wave within group (q-quarter)
    const int l31  = lane & 31;
    const int hh   = lane >> 5;

    const int bid = blockIdx.x;
    const int xcd = bid & 7, j = bid >> 3;
    const int qt  = j & 15;
    const int bhg = xcd + 8 * (j >> 4);          // 0..31
    const int q0  = qt * 128;
    const size_t bh = (size_t)bhg;

    const char* qP = (const char*)(qB + bh * SEQ * HD);
    const char* kP = (const char*)(kB + bh * SEQ * HD);
    const char* vP = (const char*)(vtB + bh * SEQ * HD);

    const int ringb = grp * 32768;
    const int wb    = wql * 1024;
    const int tg    = t & 255;

    {   // Q: 128 rows x 128B into [49152, 65536) = ring1 buf1 (transient)
        int rr = t >> 3, cc = t & 7;   // rr 0..63
        #pragma unroll
        for (int i = 0; i < 2; ++i) {
            int row = i * 64 + rr;
            int ch  = cc ^ (row & 7);
            gl16(qP + (size_t)(q0 + row) * 128 + ch * 16,
                 smem + 49152 + i * 8192 + wq * 1024);
        }
    }
    // stage pair p (global) into own ring buf: Ka@0 Kb@4K Va@8K Vb@12K
    auto stageP = [&](int buf, int p) {
        int base = ringb + buf * 16384;
        int rr = tg >> 3;
        int ch = (tg & 7) ^ (rr & 7);
        gl16(kP + (size_t)(p * 64 + rr) * 128 + ch * 16,      smem + base +     0 + wb);
        gl16(kP + (size_t)(p * 64 + 32 + rr) * 128 + ch * 16, smem + base +  4096 + wb);
        int rr2 = tg >> 2;
        int s4  = (rr2 & 3) ^ ((rr2 >> 2) & 3);
        int ch2 = (tg & 3) ^ s4;
        gl16(vP + (size_t)rr2 * (SEQ * 2) + p * 128 +      ch2 * 16, smem + base +  8192 + wb);
        gl16(vP + (size_t)rr2 * (SEQ * 2) + p * 128 + 64 + ch2 * 16, smem + base + 12288 + wb);
    };
    const int p0 = grp * (NPAIR / 2);
    stageP(0, p0);          // group0 -> [0,16K), group1 -> [32K,48K): no Q overlap
    WAIT_VM(4);             // Q's 2 loads (oldest) landed
    BARRIER();

    short8 qf[4];
    {
        int qrow = 32 * wql + l31;
        #pragma unroll
        for (int ks = 0; ks < 4; ++ks) {
            int ch = ((2 * ks + hh) ^ (qrow & 7)) * 16;
            qf[ks] = *(const short8*)(smem + 49152 + qrow * 128 + ch);
        }
    }
    asm volatile("s_waitcnt lgkmcnt(0)" ::: "memory");   // hoist complete
    __builtin_amdgcn_sched_barrier(0);
    BARRIER();              // all waves hoisted before iter0 stages ring1-buf1

    f32x16 acc0 = {}, acc1 = {};
    float lsum = 0.0f;

    for (int i = 0; i < NPAIR / 2; ++i) {
        if (i + 1 < NPAIR / 2) { stageP((i + 1) & 1, p0 + i + 1); WAIT_VM(4); }
        else                   { WAIT_VM(0); }
        BARRIER();

        const char* Pb = smem + ringb + (i & 1) * 16384;

        // --- QK^T, both tiles of the pair ---
        f32x16 sa = {}, sb = {};
        __builtin_amdgcn_s_setprio(1);
        #pragma unroll
        for (int ks = 0; ks < 4; ++ks) {
            int ch = ((2 * ks + hh) ^ (l31 & 7)) * 16;
            short8 ka = *(const short8*)(Pb +        l31 * 128 + ch);
            short8 kb = *(const short8*)(Pb + 4096 + l31 * 128 + ch);
            sa = __builtin_amdgcn_mfma_f32_32x32x16_bf16(ka, qf[ks], sa, 0, 0, 0);
            sb = __builtin_amdgcn_mfma_f32_32x32x16_bf16(kb, qf[ks], sb, 0, 0, 0);
        }
        __builtin_amdgcn_s_setprio(0);

        // --- exp2 direct + pack + own-half sums ---
        unsigned int pa_[8], pb_[8];
        float ps0 = 0.f, ps1 = 0.f, ps2 = 0.f, ps3 = 0.f;
        #pragma unroll
        for (int w = 0; w < 8; ++w) {
            float e0 = __builtin_amdgcn_exp2f(sa[2 * w]);
            float e1 = __builtin_amdgcn_exp2f(sa[2 * w + 1]);
            ps0 += e0; ps1 += e1;
            pa_[w] = cvt_pk_bf16(e0, e1);
            float f0 = __builtin_amdgcn_exp2f(sb[2 * w]);
            float f1 = __builtin_amdgcn_exp2f(sb[2 * w + 1]);
            ps2 += f0; ps3 += f1;
            pb_[w] = cvt_pk_bf16(f0, f1);
        }
        lsum += (ps0 + ps1) + (ps2 + ps3);

        // --- PV, both tiles; B-frags via permlane32 half-swap ---
        const char* Va = Pb + 8192;
        const char* Vb = Pb + 12288;
        __builtin_amdgcn_s_setprio(1);
        #pragma unroll
        for (int ks = 0; ks < 2; ++ks) {
            unsigned int a0 = pa_[4*ks],     a2 = pa_[4*ks + 2];
            unsigned int a1 = pa_[4*ks + 1], a3 = pa_[4*ks + 3];
            asm volatile("v_permlane32_swap_b32 %0, %1" : "+v"(a0), "+v"(a2));
            asm volatile("v_permlane32_swap_b32 %0, %1" : "+v"(a1), "+v"(a3));
            unsigned int b0 = pb_[4*ks],     b2 = pb_[4*ks + 2];
            unsigned int b1 = pb_[4*ks + 1], b3 = pb_[4*ks + 3];
            asm volatile("v_permlane32_swap_b32 %0, %1" : "+v"(b0), "+v"(b2));
            asm volatile("v_permlane32_swap_b32 %0, %1" : "+v"(b1), "+v"(b3));
            short8 pA = __builtin_bit_cast(short8, make_uint4(a0, a1, a2, a3));
            short8 pB = __builtin_bit_cast(short8, make_uint4(b0, b1, b2, b3));
            #pragma unroll
            for (int mt = 0; mt < 2; ++mt) {
                int rrow = 32 * mt + l31;
                int s4   = (rrow & 3) ^ ((rrow >> 2) & 3);
                int ch   = ((2 * ks + hh) ^ s4) * 16;
                short8 va = *(const short8*)(Va + rrow * 64 + ch);
                short8 vb = *(const short8*)(Vb + rrow * 64 + ch);
                if (mt == 0) {
                    acc0 = __builtin_amdgcn_mfma_f32_32x32x16_bf16(va, pA, acc0, 0, 0, 0);
                    acc0 = __builtin_amdgcn_mfma_f32_32x32x16_bf16(vb, pB, acc0, 0, 0, 0);
                } else {
                    acc1 = __builtin_amdgcn_mfma_f32_32x32x16_bf16(va, pA, acc1, 0, 0, 0);
                    acc1 = __builtin_amdgcn_mfma_f32_32x32x16_bf16(vb, pB, acc1, 0, 0, 0);
                }
            }
        }
        __builtin_amdgcn_s_setprio(0);
        BARRIER();   // compute(i) done before next iter's stage hits buf (i+1)&1
    }

    // --- merge: group1 -> LDS (lane-major, conflict-free), group0 adds ---
    lsum += __shfl_xor(lsum, 32, 64);
    __syncthreads();
    const int qrow = 32 * wql + l31;
    if (grp == 1) {
        int idx = t - 256;
        #pragma unroll
        for (int m2 = 0; m2 < 4; ++m2) {
            *(float4*)(smem + 16384 + (m2 * 256 + idx) * 16) =
                make_float4(acc0[4*m2+0], acc0[4*m2+1], acc0[4*m2+2], acc0[4*m2+3]);
            *(float4*)(smem + 16384 + ((m2 + 4) * 256 + idx) * 16) =
                make_float4(acc1[4*m2+0], acc1[4*m2+1], acc1[4*m2+2], acc1[4*m2+3]);
        }
        if (hh == 0) ((float*)(smem + 65536))[qrow] = lsum;
    }
    __syncthreads();
    if (grp == 0) {
        float l1 = ((float*)(smem + 65536))[qrow];
        float inv = 1.0f / (lsum + l1);
        #pragma unroll
        for (int m2 = 0; m2 < 4; ++m2) {
            float4 pa = *(const float4*)(smem + 16384 + (m2 * 256 + t) * 16);
            float4 pb = *(const float4*)(smem + 16384 + ((m2 + 4) * 256 + t) * 16);
            ushort4 h4a, h4b;
            h4a.x = f2bf((acc0[4*m2+0] + pa.x) * inv);
            h4a.y = f2bf((acc0[4*m2+1] + pa.y) * inv);
            h4a.z = f2bf((acc0[4*m2+2] + pa.z) * inv);
            h4a.w = f2bf((acc0[4*m2+3] + pa.w) * inv);
            h4b.x = f2bf((acc1[4*m2+0] + pb.x) * inv);
            h4b.y = f2bf((acc1[4*m2+1] + pb.y) * inv);
            h4b.z = f2bf((acc1[4*m2+2] + pb.z) * inv);
            h4b.w = f2bf((acc1[4*m2+3] + pb.w) * inv);
            int d0a = 4 * hh + 8 * m2;
            int ca  = (d0a >> 3) ^ (qrow & 7);
            *(ushort4*)(smem + qrow * 128 + ca * 16 + (d0a & 7) * 2) = h4a;
            int d0b = 4 * hh + 8 * m2 + 32;
            int cb  = (d0b >> 3) ^ (qrow & 7);
            *(ushort4*)(smem + qrow * 128 + cb * 16 + (d0b & 7) * 2) = h4b;
        }
    }
    __syncthreads();
    {
        #pragma unroll
        for (int it = 0; it < 2; ++it) {
            int slot = it * 512 + t;
            int row  = slot >> 3;
            int p    = slot & 7;
            uint4 v4 = *(const uint4*)(smem + row * 128 + ((p ^ (row & 7)) * 16));
            *(uint4*)&ctxb[((size_t)(bhg >> 4) * SEQ + q0 + row) * HIDDEN
                           + (bhg & 15) * HD + p * 8] = v4;
        }
    }
}

// ---------------------------------------------------------------------------
extern "C" void kernel_launch(void* const* d_in, const int* in_sizes, int n_in,
                              void* d_out, int out_size, void* d_ws, size_t ws_size,
                              hipStream_t stream)
{
    const float* x     = (const float*)d_in[0];
    const float* w_qkv = (const float*)d_in[1];
    const float* b_qkv = (const float*)d_in[2];
    const float* w_out = (const float*)d_in[3];
    const float* b_out = (const float*)d_in[4];
    float* out = (float*)d_out;

    const size_t PH = (size_t)BATCH * HEADS * SEQ * HD;   // 4,194,304 elems/plane
    unsigned short* ws = (unsigned short*)d_ws;
    unsigned short* qB  = ws;                  // [0, PH)
    unsigned short* kB  = ws + PH;             // [PH, 2PH)
    unsigned short* vtB = ws + 2 * PH;         // [2PH, 3PH)
    unsigned short* wqh = ws + 3 * PH;         // [3PH, 3.75PH)
    unsigned short* woh = wqh + 3 * PH / 4;    // [3.75PH, 4PH)
    unsigned short* cth = woh + PH / 4;        // [4PH, 6PH)  ctx bf16
    unsigned short* xh  = (unsigned short*)d_out;  // x-hi lives in d_out

    conv_all<<<8192, 256, 0, stream>>>(x, xh, w_qkv, wqh, w_out, woh);
    qkv_gemm<<<dim3(32, 24), 256, 0, stream>>>(xh, wqh, b_qkv, qB, kB, vtB);
    attn_mfma<<<512, 512, 0, stream>>>(qB, kB, vtB, cth);
    out_gemm<<<dim3(32, 8), 256, 0, stream>>>(cth, woh, b_out, out);
}